// Round 3
// baseline (545.951 us; speedup 1.0000x reference)
//
#include <hip/hip_runtime.h>
#include <hip/hip_bf16.h>

// round 3 resubmit (rounds 1-2 died on an unresponsive container before compile)

#define B_ 4
#define C_ 256
#define ND_ 81   // 9*9 displacement channels

typedef float  f32x4 __attribute__((ext_vector_type(4)));
typedef float  f32x2 __attribute__((ext_vector_type(2)));
typedef unsigned int u32x4 __attribute__((ext_vector_type(4)));
typedef __bf16 bf16x8 __attribute__((ext_vector_type(8)));

__device__ __forceinline__ unsigned short f2bf(float f) {
  unsigned int u = __builtin_bit_cast(unsigned int, f);
  u += 0x7FFFu + ((u >> 16) & 1u);   // RNE
  return (unsigned short)(u >> 16);
}

// ---------------- 2x2 average pooling (fmaps fp32 ch-major + depths) ----------------
template<int Ho, int Wo>
__global__ void pool_level(const float* __restrict__ f1i, const float* __restrict__ f2i,
                           const float* __restrict__ d1i, const float* __restrict__ d2i,
                           float* __restrict__ f1o, float* __restrict__ f2o,
                           float* __restrict__ d1o, float* __restrict__ d2o) {
  constexpr long HWo   = (long)Ho * Wo;
  constexpr long sizeF = (long)B_ * C_ * HWo;
  constexpr long sizeD = (long)B_ * HWo;
  constexpr long N     = 2 * sizeF + 2 * sizeD;
  long idx = (long)blockIdx.x * blockDim.x + threadIdx.x;
  if (idx >= N) return;
  const float* src; float* dst; long r = idx;
  if      (r < sizeF)           { src = f1i; dst = f1o; }
  else if (r < 2*sizeF)         { src = f2i; dst = f2o; r -= sizeF; }
  else if (r < 2*sizeF + sizeD) { src = d1i; dst = d1o; r -= 2*sizeF; }
  else                          { src = d2i; dst = d2o; r -= 2*sizeF + sizeD; }
  long plane = r / HWo;                 // constexpr divisor -> magic mul
  long pix   = r - plane * HWo;
  int  yo    = (int)(pix / Wo);
  int  xo    = (int)(pix - (long)yo * Wo);
  constexpr int Wi = 2 * Wo;
  const float* p0 = src + (plane * (2 * Ho) + 2 * yo) * (long)Wi + 2 * xo;
  f32x2 a = *(const f32x2*)p0;
  f32x2 c = *(const f32x2*)(p0 + Wi);
  dst[r] = 0.25f * (a.x + a.y + c.x + c.y);
}

// ------- normalize over C + transpose to pixel-major bf16 (one block = 64 pixels of a row) -------
__global__ void norm_tp(const float* __restrict__ src1, const float* __restrict__ src2,
                        unsigned short* __restrict__ dst1, unsigned short* __restrict__ dst2,
                        int H, int W) {
  __shared__ unsigned short raw[64 * 258];   // [pixel][c], pad 258 -> 2-way (free) banks
  __shared__ float ssp[4][64];
  __shared__ float inv[64];
  int tid = threadIdx.x;
  int lane = tid & 63, w = tid >> 6;
  int x0 = blockIdx.x * 64, y = blockIdx.y;
  int z = blockIdx.z, b = z >> 1;
  const float* src = (z & 1) ? src2 : src1;
  unsigned short* dst = (z & 1) ? dst2 : dst1;
  int x = x0 + lane;
  bool ok = x < W;
  long HW = (long)H * W;
  const float* base = src + ((long)b * C_) * HW + (long)y * W + x;
  float ss = 0.f;
  for (int cc = 0; cc < 64; ++cc) {
    int c = w * 64 + cc;
    float v = ok ? base[(long)c * HW] : 0.f;   // coalesced over lanes (x)
    ss += v * v;
    raw[lane * 258 + c] = f2bf(v);
  }
  ssp[w][lane] = ss;
  __syncthreads();
  if (tid < 64) {
    float s = ssp[0][tid] + ssp[1][tid] + ssp[2][tid] + ssp[3][tid];
    inv[tid] = 1.f / fmaxf(sqrtf(s), 1e-12f);
  }
  __syncthreads();
  // write pixel-major: thread tid owns channel c = tid for all 64 pixels
  unsigned short* drow = dst + ((long)b * HW + (long)y * W + x0) * C_ + tid;
  for (int p = 0; p < 64; ++p) {
    if (x0 + p < W) {
      float v = __builtin_bit_cast(float, ((unsigned int)raw[p * 258 + tid]) << 16) * inv[p];
      drow[(long)p * C_] = f2bf(v);
    }
  }
}

// ---------------- local-window correlation via MFMA 16x16x32 bf16 ----------------
// block = 4 waves; wave w handles q-row y0+w, 16 q-pixels x0..x0+15 (M dim).
// N dim = window columns x0-4 .. x0+27 (2 n-tiles of 16; cols 24..31 computed, discarded).
__global__ __launch_bounds__(256, 2) void corr_kernel(
    const unsigned short* __restrict__ f1n, const unsigned short* __restrict__ f2n,
    const float* __restrict__ d1, const float* __restrict__ d2,
    const float* __restrict__ dwp, float* __restrict__ out, int H, int W) {
  __shared__ float lds_o[64 * ND_];
  __shared__ float dt[64];
  int tid = threadIdx.x;
  int lane = tid & 63, wv = tid >> 6;
  int x0 = blockIdx.x * 16, y0 = blockIdx.y * 4, b = blockIdx.z;
  int y = y0 + wv;
  int n16 = lane & 15, hi = lane >> 4;
  long HW = (long)H * W;

  // A fragments: f1n[b][y][x0+m][c], lane m=l&15, k = hi*8+j
  int xm = x0 + n16;
  bool aok = xm < W;
  const unsigned short* abase = f1n + ((long)b * HW + (long)y * W + xm) * C_ + hi * 8;
  bf16x8 afr[8];
#pragma unroll
  for (int ch = 0; ch < 8; ++ch) {
    u32x4 rr = {0u, 0u, 0u, 0u};
    if (aok) rr = *(const u32x4*)(abase + ch * 32);
    afr[ch] = __builtin_bit_cast(bf16x8, rr);
  }

  f32x4 acc[9][2];
#pragma unroll
  for (int dy = 0; dy < 9; ++dy)
#pragma unroll
    for (int nt = 0; nt < 2; ++nt)
      acc[dy][nt] = f32x4{0.f, 0.f, 0.f, 0.f};

#pragma unroll
  for (int dy = 0; dy < 9; ++dy) {
    int yy = y + dy - 4;
    if (yy >= 0 && yy < H) {
      const unsigned short* brow = f2n + ((long)b * HW + (long)yy * W) * C_;
#pragma unroll
      for (int nt = 0; nt < 2; ++nt) {
        int wx = x0 - 4 + nt * 16 + n16;
        bool bok = (wx >= 0) && (wx < W);
        const unsigned short* bbase = brow + (long)wx * C_ + hi * 8;
        bf16x8 bfr[8];
#pragma unroll
        for (int ch = 0; ch < 8; ++ch) {
          u32x4 rr = {0u, 0u, 0u, 0u};
          if (bok) rr = *(const u32x4*)(bbase + ch * 32);
          bfr[ch] = __builtin_bit_cast(bf16x8, rr);
        }
#pragma unroll
        for (int ch = 0; ch < 8; ++ch)
          acc[dy][nt] = __builtin_amdgcn_mfma_f32_16x16x32_bf16(afr[ch], bfr[ch], acc[dy][nt], 0, 0, 0);
      }
    }
  }

  // stage D -> LDS. D layout: lane l, reg r -> m=(l>>4)*4+r (row), n=l&15 (col).
  // ref channel: f2p[r-dy+y] = f2n[y-dy]  =>  d = (8-dy)*9 + (4-dx)
#pragma unroll
  for (int dy = 0; dy < 9; ++dy)
#pragma unroll
    for (int nt = 0; nt < 2; ++nt)
#pragma unroll
      for (int r = 0; r < 4; ++r) {
        int m = hi * 4 + r;
        int dx = nt * 16 + n16 - m - 4;        // -4..4 valid
        if (dx >= -4 && dx <= 4) {
          int d = (8 - dy) * 9 + (4 - dx);
          lds_o[(wv * 16 + m) * ND_ + d] = acc[dy][nt][r];
        }
      }
  // depth affinity per pixel
  if (tid < 64) {
    int ty = tid >> 4, tx = tid & 15;
    int xq = x0 + tx, yq = y0 + ty;
    float v = 0.f;
    if (xq < W) {
      long pidx = (long)b * HW + (long)yq * W + xq;
      v = dwp[0] * expf(-fabsf(d1[pidx] - d2[pidx]));
    }
    dt[tid] = v;
  }
  __syncthreads();
  // coalesced writeout: each 64-lane group handles one d-plane slice of the 4x16 tile
  long obase = (long)b * ND_ * HW;
  for (int it = 0; it < 21; ++it) {
    int flat = it * 256 + tid;
    if (flat < 64 * ND_) {
      int d = flat >> 6;
      int p = flat & 63;
      int xq = x0 + (p & 15);
      if (xq < W)
        out[obase + (long)d * HW + (long)(y0 + (p >> 4)) * W + xq] = lds_o[p * ND_ + d] + dt[p];
    }
  }
}

// ---------------------------------------------------------------------------
extern "C" void kernel_launch(void* const* d_in, const int* in_sizes, int n_in,
                              void* d_out, int out_size, void* d_ws, size_t ws_size,
                              hipStream_t stream) {
  const float* f1  = (const float*)d_in[0];
  const float* f2  = (const float*)d_in[1];
  const float* dp1 = (const float*)d_in[2];
  const float* dp2 = (const float*)d_in[3];
  const float* dw  = (const float*)d_in[4];
  float* out = (float*)d_out;

  static const long HWs[4] = {25600, 6400, 1600, 400};

  char* ws = (char*)d_ws;
  size_t off = 0;
  auto alloc = [&](size_t bytes) -> void* {
    void* p = ws + off;
    off = (off + bytes + 255) & ~(size_t)255;
    return p;
  };
  float* f1p[4]; float* f2p[4]; float* d1p[4]; float* d2p[4];
  for (int l = 1; l <= 3; ++l) f1p[l] = (float*)alloc((size_t)B_ * C_ * HWs[l] * 4);
  for (int l = 1; l <= 3; ++l) f2p[l] = (float*)alloc((size_t)B_ * C_ * HWs[l] * 4);
  for (int l = 1; l <= 3; ++l) d1p[l] = (float*)alloc((size_t)B_ * HWs[l] * 4);
  for (int l = 1; l <= 3; ++l) d2p[l] = (float*)alloc((size_t)B_ * HWs[l] * 4);
  unsigned short* f1n[4]; unsigned short* f2n[4];
  for (int l = 0; l < 4; ++l) f1n[l] = (unsigned short*)alloc((size_t)B_ * HWs[l] * C_ * 2);
  for (int l = 0; l < 4; ++l) f2n[l] = (unsigned short*)alloc((size_t)B_ * HWs[l] * C_ * 2);
  if (off > ws_size) return;   // workspace too small: bail (clean failure)

  // 1) pooling pyramid (fmaps + depths), iterative 2x2
  pool_level<80, 80><<<dim3((13158400 + 255) / 256), 256, 0, stream>>>(
      f1, f2, dp1, dp2, f1p[1], f2p[1], d1p[1], d2p[1]);
  pool_level<40, 40><<<dim3((3289600 + 255) / 256), 256, 0, stream>>>(
      f1p[1], f2p[1], d1p[1], d2p[1], f1p[2], f2p[2], d1p[2], d2p[2]);
  pool_level<20, 20><<<dim3((822400 + 255) / 256), 256, 0, stream>>>(
      f1p[2], f2p[2], d1p[2], d2p[2], f1p[3], f2p[3], d1p[3], d2p[3]);

  // 2) normalize + transpose to bf16 pixel-major
  norm_tp<<<dim3(3, 160, 8), 256, 0, stream>>>(f1,     f2,     f1n[0], f2n[0], 160, 160);
  norm_tp<<<dim3(2,  80, 8), 256, 0, stream>>>(f1p[1], f2p[1], f1n[1], f2n[1],  80,  80);
  norm_tp<<<dim3(1,  40, 8), 256, 0, stream>>>(f1p[2], f2p[2], f1n[2], f2n[2],  40,  40);
  norm_tp<<<dim3(1,  20, 8), 256, 0, stream>>>(f1p[3], f2p[3], f1n[3], f2n[3],  20,  20);

  // 3) correlation volumes + depth term
  corr_kernel<<<dim3(10, 40, 4), 256, 0, stream>>>(f1n[0], f2n[0], dp1,    dp2,    dw, out,            160, 160);
  corr_kernel<<<dim3( 5, 20, 4), 256, 0, stream>>>(f1n[1], f2n[1], d1p[1], d2p[1], dw, out +  8294400,  80,  80);
  corr_kernel<<<dim3( 3, 10, 4), 256, 0, stream>>>(f1n[2], f2n[2], d1p[2], d2p[2], dw, out + 10368000,  40,  40);
  corr_kernel<<<dim3( 2,  5, 4), 256, 0, stream>>>(f1n[3], f2n[3], d1p[3], d2p[3], dw, out + 10886400,  20,  20);
}

// Round 4
// 362.840 us; speedup vs baseline: 1.5047x; 1.5047x over previous
//
#include <hip/hip_runtime.h>
#include <hip/hip_bf16.h>

// round 4: norm_tp rewrite — 16-deep load batching + vectorized LDS/global phase B
// (baseline r3: 546 us passed; norm_tp L0 was 150 us at 17% HBM, VGPR=12 latency-bound)

#define B_ 4
#define C_ 256
#define ND_ 81   // 9*9 displacement channels

typedef float  f32x4 __attribute__((ext_vector_type(4)));
typedef float  f32x2 __attribute__((ext_vector_type(2)));
typedef unsigned int u32x4 __attribute__((ext_vector_type(4)));
typedef __bf16 bf16x8 __attribute__((ext_vector_type(8)));
typedef unsigned short u16x4 __attribute__((ext_vector_type(4)));

__device__ __forceinline__ unsigned short f2bf(float f) {
  unsigned int u = __builtin_bit_cast(unsigned int, f);
  u += 0x7FFFu + ((u >> 16) & 1u);   // RNE
  return (unsigned short)(u >> 16);
}

// ---------------- 2x2 average pooling (fmaps fp32 ch-major + depths) ----------------
template<int Ho, int Wo>
__global__ void pool_level(const float* __restrict__ f1i, const float* __restrict__ f2i,
                           const float* __restrict__ d1i, const float* __restrict__ d2i,
                           float* __restrict__ f1o, float* __restrict__ f2o,
                           float* __restrict__ d1o, float* __restrict__ d2o) {
  constexpr long HWo   = (long)Ho * Wo;
  constexpr long sizeF = (long)B_ * C_ * HWo;
  constexpr long sizeD = (long)B_ * HWo;
  constexpr long N     = 2 * sizeF + 2 * sizeD;
  long idx = (long)blockIdx.x * blockDim.x + threadIdx.x;
  if (idx >= N) return;
  const float* src; float* dst; long r = idx;
  if      (r < sizeF)           { src = f1i; dst = f1o; }
  else if (r < 2*sizeF)         { src = f2i; dst = f2o; r -= sizeF; }
  else if (r < 2*sizeF + sizeD) { src = d1i; dst = d1o; r -= 2*sizeF; }
  else                          { src = d2i; dst = d2o; r -= 2*sizeF + sizeD; }
  long plane = r / HWo;                 // constexpr divisor -> magic mul
  long pix   = r - plane * HWo;
  int  yo    = (int)(pix / Wo);
  int  xo    = (int)(pix - (long)yo * Wo);
  constexpr int Wi = 2 * Wo;
  const float* p0 = src + (plane * (2 * Ho) + 2 * yo) * (long)Wi + 2 * xo;
  f32x2 a = *(const f32x2*)p0;
  f32x2 c = *(const f32x2*)(p0 + Wi);
  dst[r] = 0.25f * (a.x + a.y + c.x + c.y);
}

// ------- normalize over C + transpose to pixel-major bf16 -------
// block = 64 flat pixels; phase A: lane=pixel, 16-deep batched channel loads -> LDS bf16.
// phase B: lane=c4 slot, thread walks 16 pixels; ds_read_b64 + 8B global store per step.
__global__ __launch_bounds__(256) void norm_tp(
    const float* __restrict__ src1, const float* __restrict__ src2,
    unsigned short* __restrict__ dst1, unsigned short* __restrict__ dst2, int HW_) {
  __shared__ unsigned short raw[64 * 260];   // [pixel][c], pad 260 keeps 8B row alignment
  __shared__ float ssp[4][64];
  __shared__ float inv[64];
  int tid = threadIdx.x;
  int lane = tid & 63, w = tid >> 6;
  long HW = HW_;
  long pix0 = (long)blockIdx.x * 64;
  int z = blockIdx.z, b = z >> 1;
  const float* src = (z & 1) ? src2 : src1;
  unsigned short* dst = (z & 1) ? dst2 : dst1;
  bool ok = (pix0 + lane) < HW;                 // only block 6 at L3 has OOB
  const float* base = src + (long)b * C_ * HW + pix0 + lane;

  float ss = 0.f;
  float vv[16];
  for (int cb = 0; cb < 64; cb += 16) {
    int c0 = w * 64 + cb;
#pragma unroll
    for (int j = 0; j < 16; ++j)
      vv[j] = ok ? base[(long)(c0 + j) * HW] : 0.f;   // 16 outstanding coalesced loads
#pragma unroll
    for (int g = 0; g < 4; ++g) {
      u16x4 pk;
#pragma unroll
      for (int j = 0; j < 4; ++j) {
        float v = vv[g * 4 + j];
        ss += v * v;
        pk[j] = f2bf(v);
      }
      *(u16x4*)&raw[lane * 260 + c0 + g * 4] = pk;    // ds_write_b64
    }
  }
  ssp[w][lane] = ss;
  __syncthreads();
  if (tid < 64) {
    float s = ssp[0][tid] + ssp[1][tid] + ssp[2][tid] + ssp[3][tid];
    inv[tid] = 1.f / fmaxf(sqrtf(s), 1e-12f);
  }
  __syncthreads();

  // phase B: wave w handles pixels {w, w+4, ..., w+60}; lane covers channels lane*4..+3
  int c4 = lane * 4;
  unsigned short* dbase = dst + ((long)b * HW + pix0) * C_;
  for (int p = w; p < 64; p += 4) {
    if (pix0 + p < HW) {
      u16x4 r = *(const u16x4*)&raw[p * 260 + c4];    // ds_read_b64, contiguous per wave
      float sc = inv[p];
      u16x4 o;
#pragma unroll
      for (int j = 0; j < 4; ++j) {
        float v = __builtin_bit_cast(float, ((unsigned int)r[j]) << 16) * sc;
        o[j] = f2bf(v);
      }
      *(u16x4*)&dbase[(long)p * C_ + c4] = o;         // 8B store, contiguous per wave
    }
  }
}

// ---------------- local-window correlation via MFMA 16x16x32 bf16 ----------------
// block = 4 waves; wave w handles q-row y0+w, 16 q-pixels x0..x0+15 (M dim).
// N dim = window columns x0-4 .. x0+27 (2 n-tiles of 16; cols 24..31 computed, discarded).
__global__ __launch_bounds__(256, 2) void corr_kernel(
    const unsigned short* __restrict__ f1n, const unsigned short* __restrict__ f2n,
    const float* __restrict__ d1, const float* __restrict__ d2,
    const float* __restrict__ dwp, float* __restrict__ out, int H, int W) {
  __shared__ float lds_o[64 * ND_];
  __shared__ float dt[64];
  int tid = threadIdx.x;
  int lane = tid & 63, wv = tid >> 6;
  int x0 = blockIdx.x * 16, y0 = blockIdx.y * 4, b = blockIdx.z;
  int y = y0 + wv;
  int n16 = lane & 15, hi = lane >> 4;
  long HW = (long)H * W;

  // A fragments: f1n[b][y][x0+m][c], lane m=l&15, k = hi*8+j
  int xm = x0 + n16;
  bool aok = xm < W;
  const unsigned short* abase = f1n + ((long)b * HW + (long)y * W + xm) * C_ + hi * 8;
  bf16x8 afr[8];
#pragma unroll
  for (int ch = 0; ch < 8; ++ch) {
    u32x4 rr = {0u, 0u, 0u, 0u};
    if (aok) rr = *(const u32x4*)(abase + ch * 32);
    afr[ch] = __builtin_bit_cast(bf16x8, rr);
  }

  f32x4 acc[9][2];
#pragma unroll
  for (int dy = 0; dy < 9; ++dy)
#pragma unroll
    for (int nt = 0; nt < 2; ++nt)
      acc[dy][nt] = f32x4{0.f, 0.f, 0.f, 0.f};

#pragma unroll
  for (int dy = 0; dy < 9; ++dy) {
    int yy = y + dy - 4;
    if (yy >= 0 && yy < H) {
      const unsigned short* brow = f2n + ((long)b * HW + (long)yy * W) * C_;
#pragma unroll
      for (int nt = 0; nt < 2; ++nt) {
        int wx = x0 - 4 + nt * 16 + n16;
        bool bok = (wx >= 0) && (wx < W);
        const unsigned short* bbase = brow + (long)wx * C_ + hi * 8;
        bf16x8 bfr[8];
#pragma unroll
        for (int ch = 0; ch < 8; ++ch) {
          u32x4 rr = {0u, 0u, 0u, 0u};
          if (bok) rr = *(const u32x4*)(bbase + ch * 32);
          bfr[ch] = __builtin_bit_cast(bf16x8, rr);
        }
#pragma unroll
        for (int ch = 0; ch < 8; ++ch)
          acc[dy][nt] = __builtin_amdgcn_mfma_f32_16x16x32_bf16(afr[ch], bfr[ch], acc[dy][nt], 0, 0, 0);
      }
    }
  }

  // stage D -> LDS. D layout: lane l, reg r -> m=(l>>4)*4+r (row), n=l&15 (col).
  // ref channel: f2p[r-dy+y] = f2n[y-dy]  =>  d = (8-dy)*9 + (4-dx)
#pragma unroll
  for (int dy = 0; dy < 9; ++dy)
#pragma unroll
    for (int nt = 0; nt < 2; ++nt)
#pragma unroll
      for (int r = 0; r < 4; ++r) {
        int m = hi * 4 + r;
        int dx = nt * 16 + n16 - m - 4;        // -4..4 valid
        if (dx >= -4 && dx <= 4) {
          int d = (8 - dy) * 9 + (4 - dx);
          lds_o[(wv * 16 + m) * ND_ + d] = acc[dy][nt][r];
        }
      }
  // depth affinity per pixel
  if (tid < 64) {
    int ty = tid >> 4, tx = tid & 15;
    int xq = x0 + tx, yq = y0 + ty;
    float v = 0.f;
    if (xq < W) {
      long pidx = (long)b * HW + (long)yq * W + xq;
      v = dwp[0] * expf(-fabsf(d1[pidx] - d2[pidx]));
    }
    dt[tid] = v;
  }
  __syncthreads();
  // coalesced writeout: each 64-lane group handles one d-plane slice of the 4x16 tile
  long obase = (long)b * ND_ * HW;
  for (int it = 0; it < 21; ++it) {
    int flat = it * 256 + tid;
    if (flat < 64 * ND_) {
      int d = flat >> 6;
      int p = flat & 63;
      int xq = x0 + (p & 15);
      if (xq < W)
        out[obase + (long)d * HW + (long)(y0 + (p >> 4)) * W + xq] = lds_o[p * ND_ + d] + dt[p];
    }
  }
}

// ---------------------------------------------------------------------------
extern "C" void kernel_launch(void* const* d_in, const int* in_sizes, int n_in,
                              void* d_out, int out_size, void* d_ws, size_t ws_size,
                              hipStream_t stream) {
  const float* f1  = (const float*)d_in[0];
  const float* f2  = (const float*)d_in[1];
  const float* dp1 = (const float*)d_in[2];
  const float* dp2 = (const float*)d_in[3];
  const float* dw  = (const float*)d_in[4];
  float* out = (float*)d_out;

  static const long HWs[4] = {25600, 6400, 1600, 400};

  char* ws = (char*)d_ws;
  size_t off = 0;
  auto alloc = [&](size_t bytes) -> void* {
    void* p = ws + off;
    off = (off + bytes + 255) & ~(size_t)255;
    return p;
  };
  float* f1p[4]; float* f2p[4]; float* d1p[4]; float* d2p[4];
  for (int l = 1; l <= 3; ++l) f1p[l] = (float*)alloc((size_t)B_ * C_ * HWs[l] * 4);
  for (int l = 1; l <= 3; ++l) f2p[l] = (float*)alloc((size_t)B_ * C_ * HWs[l] * 4);
  for (int l = 1; l <= 3; ++l) d1p[l] = (float*)alloc((size_t)B_ * HWs[l] * 4);
  for (int l = 1; l <= 3; ++l) d2p[l] = (float*)alloc((size_t)B_ * HWs[l] * 4);
  unsigned short* f1n[4]; unsigned short* f2n[4];
  for (int l = 0; l < 4; ++l) f1n[l] = (unsigned short*)alloc((size_t)B_ * HWs[l] * C_ * 2);
  for (int l = 0; l < 4; ++l) f2n[l] = (unsigned short*)alloc((size_t)B_ * HWs[l] * C_ * 2);
  if (off > ws_size) return;   // workspace too small: bail (clean failure)

  // 1) pooling pyramid (fmaps + depths), iterative 2x2
  pool_level<80, 80><<<dim3((13158400 + 255) / 256), 256, 0, stream>>>(
      f1, f2, dp1, dp2, f1p[1], f2p[1], d1p[1], d2p[1]);
  pool_level<40, 40><<<dim3((3289600 + 255) / 256), 256, 0, stream>>>(
      f1p[1], f2p[1], d1p[1], d2p[1], f1p[2], f2p[2], d1p[2], d2p[2]);
  pool_level<20, 20><<<dim3((822400 + 255) / 256), 256, 0, stream>>>(
      f1p[2], f2p[2], d1p[2], d2p[2], f1p[3], f2p[3], d1p[3], d2p[3]);

  // 2) normalize + transpose to bf16 pixel-major (flat-pixel blocks of 64)
  norm_tp<<<dim3(400, 1, 8), 256, 0, stream>>>(f1,     f2,     f1n[0], f2n[0], 25600);
  norm_tp<<<dim3(100, 1, 8), 256, 0, stream>>>(f1p[1], f2p[1], f1n[1], f2n[1], 6400);
  norm_tp<<<dim3( 25, 1, 8), 256, 0, stream>>>(f1p[2], f2p[2], f1n[2], f2n[2], 1600);
  norm_tp<<<dim3(  7, 1, 8), 256, 0, stream>>>(f1p[3], f2p[3], f1n[3], f2n[3], 400);

  // 3) correlation volumes + depth term
  corr_kernel<<<dim3(10, 40, 4), 256, 0, stream>>>(f1n[0], f2n[0], dp1,    dp2,    dw, out,            160, 160);
  corr_kernel<<<dim3( 5, 20, 4), 256, 0, stream>>>(f1n[1], f2n[1], d1p[1], d2p[1], dw, out +  8294400,  80,  80);
  corr_kernel<<<dim3( 3, 10, 4), 256, 0, stream>>>(f1n[2], f2n[2], d1p[2], d2p[2], dw, out + 10368000,  40,  40);
  corr_kernel<<<dim3( 2,  5, 4), 256, 0, stream>>>(f1n[3], f2n[3], d1p[3], d2p[3], dw, out + 10886400,  20,  20);
}

// Round 7
// 279.495 us; speedup vs baseline: 1.9533x; 1.2982x over previous
//
#include <hip/hip_runtime.h>
#include <hip/hip_bf16.h>

// r7 = r6 with ALL ws buffers distinct (no aliasing/carving).
// Lesson (r5 NaN, r6 replay-only corruption): reusing a ws address range for
// different logical content lets stale per-XCD L2 lines surface; content-stable
// (single-writer, replay-invariant) buffers are safe. 216.47 MB total.

#define B_ 4
#define C_ 256
#define ND_ 81

typedef float  f32x4 __attribute__((ext_vector_type(4)));
typedef float  f32x2 __attribute__((ext_vector_type(2)));
typedef unsigned int u32x4 __attribute__((ext_vector_type(4)));
typedef __bf16 bf16x8 __attribute__((ext_vector_type(8)));
typedef unsigned short u16x4 __attribute__((ext_vector_type(4)));

__device__ __forceinline__ unsigned short f2bf(float f) {
  unsigned int u = __builtin_bit_cast(unsigned int, f);
  u += 0x7FFFu + ((u >> 16) & 1u);   // RNE
  return (unsigned short)(u >> 16);
}

__device__ __forceinline__ void gload16(const void* g, void* l) {
  __builtin_amdgcn_global_load_lds(
      (const __attribute__((address_space(1))) unsigned int*)g,
      (__attribute__((address_space(3))) unsigned int*)l, 16, 0, 0);
}

// ---------------- 2x2 average pooling ----------------
template<int Ho, int Wo>
__global__ void pool_level(const float* __restrict__ f1i, const float* __restrict__ f2i,
                           const float* __restrict__ d1i, const float* __restrict__ d2i,
                           float* __restrict__ f1o, float* __restrict__ f2o,
                           float* __restrict__ d1o, float* __restrict__ d2o) {
  constexpr long HWo   = (long)Ho * Wo;
  constexpr long sizeF = (long)B_ * C_ * HWo;
  constexpr long sizeD = (long)B_ * HWo;
  constexpr long N     = 2 * sizeF + 2 * sizeD;
  long idx = (long)blockIdx.x * blockDim.x + threadIdx.x;
  if (idx >= N) return;
  const float* src; float* dst; long r = idx;
  if      (r < sizeF)           { src = f1i; dst = f1o; }
  else if (r < 2*sizeF)         { src = f2i; dst = f2o; r -= sizeF; }
  else if (r < 2*sizeF + sizeD) { src = d1i; dst = d1o; r -= 2*sizeF; }
  else                          { src = d2i; dst = d2o; r -= 2*sizeF + sizeD; }
  long plane = r / HWo;
  long pix   = r - plane * HWo;
  int  yo    = (int)(pix / Wo);
  int  xo    = (int)(pix - (long)yo * Wo);
  constexpr int Wi = 2 * Wo;
  const float* p0 = src + (plane * (2 * Ho) + 2 * yo) * (long)Wi + 2 * xo;
  f32x2 a = *(const f32x2*)p0;
  f32x2 c = *(const f32x2*)(p0 + Wi);
  dst[r] = 0.25f * (a.x + a.y + c.x + c.y);
}

// ------- normalize + transpose, dst2 zero-halo-padded (L0/L1 path) -------
template<int W>
__global__ __launch_bounds__(256) void norm_tp2(
    const float* __restrict__ src1, const float* __restrict__ src2,
    unsigned short* __restrict__ dst1, unsigned short* __restrict__ dst2) {
  constexpr int HW = W * W, Wp = W + 8;
  __shared__ unsigned short raw[64 * 260];
  __shared__ float ssp[4][64];
  __shared__ float inv[64];
  int tid = threadIdx.x;
  int lane = tid & 63, w = tid >> 6;
  long pix0 = (long)blockIdx.x * 64;
  int z = blockIdx.z, b = z >> 1;
  bool pad = (z & 1) != 0;
  const float* src = pad ? src2 : src1;
  unsigned short* dst = pad ? dst2 : dst1;
  bool ok = (pix0 + lane) < HW;
  const float* base = src + (long)b * C_ * HW + pix0 + lane;

  float ss = 0.f;
  float vv[16];
  for (int cb = 0; cb < 64; cb += 16) {
    int c0 = w * 64 + cb;
#pragma unroll
    for (int j = 0; j < 16; ++j)
      vv[j] = ok ? base[(long)(c0 + j) * HW] : 0.f;
#pragma unroll
    for (int g = 0; g < 4; ++g) {
      u16x4 pk;
#pragma unroll
      for (int j = 0; j < 4; ++j) {
        float v = vv[g * 4 + j];
        ss += v * v;
        pk[j] = f2bf(v);
      }
      *(u16x4*)&raw[lane * 260 + c0 + g * 4] = pk;
    }
  }
  ssp[w][lane] = ss;
  __syncthreads();
  if (tid < 64) {
    float s = ssp[0][tid] + ssp[1][tid] + ssp[2][tid] + ssp[3][tid];
    inv[tid] = 1.f / fmaxf(sqrtf(s), 1e-12f);
  }
  __syncthreads();

  int c4 = lane * 4;
  for (int p = w; p < 64; p += 4) {
    long pix = pix0 + p;
    if (pix < HW) {
      long off;
      if (pad) {
        int y = (int)(pix / W);
        int x = (int)(pix - (long)y * W);
        off = (((long)b * Wp + (y + 4)) * Wp + (x + 4)) * C_ + c4;
      } else {
        off = ((long)b * HW + pix) * C_ + c4;
      }
      u16x4 r = *(const u16x4*)&raw[p * 260 + c4];
      float sc = inv[p];
      u16x4 o;
#pragma unroll
      for (int j = 0; j < 4; ++j) {
        float v = __builtin_bit_cast(float, ((unsigned int)r[j]) << 16) * sc;
        o[j] = f2bf(v);
      }
      *(u16x4*)&dst[off] = o;
    }
  }
}

// ------- r4-proven: normalize + transpose, both compact (L2/L3 path) -------
__global__ __launch_bounds__(256) void norm_tp_c(
    const float* __restrict__ src1, const float* __restrict__ src2,
    unsigned short* __restrict__ dst1, unsigned short* __restrict__ dst2, int HW_) {
  __shared__ unsigned short raw[64 * 260];
  __shared__ float ssp[4][64];
  __shared__ float inv[64];
  int tid = threadIdx.x;
  int lane = tid & 63, w = tid >> 6;
  long HW = HW_;
  long pix0 = (long)blockIdx.x * 64;
  int z = blockIdx.z, b = z >> 1;
  const float* src = (z & 1) ? src2 : src1;
  unsigned short* dst = (z & 1) ? dst2 : dst1;
  bool ok = (pix0 + lane) < HW;
  const float* base = src + (long)b * C_ * HW + pix0 + lane;

  float ss = 0.f;
  float vv[16];
  for (int cb = 0; cb < 64; cb += 16) {
    int c0 = w * 64 + cb;
#pragma unroll
    for (int j = 0; j < 16; ++j)
      vv[j] = ok ? base[(long)(c0 + j) * HW] : 0.f;
#pragma unroll
    for (int g = 0; g < 4; ++g) {
      u16x4 pk;
#pragma unroll
      for (int j = 0; j < 4; ++j) {
        float v = vv[g * 4 + j];
        ss += v * v;
        pk[j] = f2bf(v);
      }
      *(u16x4*)&raw[lane * 260 + c0 + g * 4] = pk;
    }
  }
  ssp[w][lane] = ss;
  __syncthreads();
  if (tid < 64) {
    float s = ssp[0][tid] + ssp[1][tid] + ssp[2][tid] + ssp[3][tid];
    inv[tid] = 1.f / fmaxf(sqrtf(s), 1e-12f);
  }
  __syncthreads();
  int c4 = lane * 4;
  unsigned short* dbase = dst + ((long)b * HW + pix0) * C_;
  for (int p = w; p < 64; p += 4) {
    if (pix0 + p < HW) {
      u16x4 r = *(const u16x4*)&raw[p * 260 + c4];
      float sc = inv[p];
      u16x4 o;
#pragma unroll
      for (int j = 0; j < 4; ++j) {
        float v = __builtin_bit_cast(float, ((unsigned int)r[j]) << 16) * sc;
        o[j] = f2bf(v);
      }
      *(u16x4*)&dbase[(long)p * C_ + c4] = o;
    }
  }
}

// ------- zero the 4px halo of a padded [b][y'][x'][c] bf16 buffer -------
template<int W>
__global__ void zero_halo(unsigned short* __restrict__ fp) {
  constexpr int Wp = W + 8;
  constexpr long UN = (long)B_ * Wp * Wp * 32;
  long u = (long)blockIdx.x * 256 + threadIdx.x;
  if (u >= UN) return;
  long px = u >> 5;
  long pp = px % ((long)Wp * Wp);
  int y = (int)(pp / Wp), x = (int)(pp - (long)(pp / Wp) * Wp);
  if (y < 4 || y >= Wp - 4 || x < 4 || x >= Wp - 4) {
    u16x4 z4 = {0, 0, 0, 0};
    *(u16x4*)&fp[u * 8] = z4;
  }
}

// ---------------- corr2: LDS-staged, K-chunked, XCD-swizzled (L0/L1) ----------------
template<int W>
__global__ __launch_bounds__(256, 3) void corr2(
    const unsigned short* __restrict__ f1n, const unsigned short* __restrict__ f2pd,
    const float* __restrict__ d1, const float* __restrict__ d2,
    const float* __restrict__ dwp, float* __restrict__ out) {
  constexpr int H = W, Wp = W + 8, Hp = H + 8;
  constexpr int GX = (W + 15) / 16, GY = H / 4;
  constexpr int NB = GX * GY * B_;
  constexpr int CPX = NB / 8;
  constexpr int BUFB = 18944;
  __shared__ char smem[2 * BUFB];
  unsigned short* sb = (unsigned short*)smem;

  int tid = threadIdx.x;
  int lane = tid & 63, wv = tid >> 6;
  int n16 = lane & 15, hi = lane >> 4;

  int f = blockIdx.x;
  int nf = (f & 7) * CPX + (f >> 3);
  int j = nf % GY;
  int rest = nf / GY;
  int i = rest % GX;
  int b = rest / GX;
  int x0 = i * 16, y0 = j * 4, y = y0 + wv;
  long HW = (long)W * H;

  int xm = x0 + n16;
  bool aok = xm < W;
  const unsigned short* abase = f1n + ((long)b * HW + (long)y * W + xm) * C_ + hi * 8;
  bf16x8 afr[8];
#pragma unroll
  for (int kc = 0; kc < 8; ++kc) {
    u32x4 rr = {0u, 0u, 0u, 0u};
    if (aok) rr = *(const u32x4*)(abase + kc * 32);
    afr[kc] = __builtin_bit_cast(bf16x8, rr);
  }

  const char* gbase = (const char*)f2pd;
  long gb[5];
#pragma unroll
  for (int it = 0; it < 5; ++it) {
    int u = tid + it * 256;
    int u2 = (u < 1152) ? u : 0;
    int sl = (u2 & ~7) | ((u2 & 7) ^ ((u2 >> 3) & 7));
    int px = sl >> 2, s = sl & 3;
    int row = px / 24, col = px - row * 24;
    int gx = x0 + col; if (gx > Wp - 1) gx = Wp - 1;
    int gy = y0 + row;
    gb[it] = (((long)b * Hp + gy) * Wp + gx) * 512 + s * 16;
  }

  f32x4 acc[9][2];
#pragma unroll
  for (int dy = 0; dy < 9; ++dy)
#pragma unroll
    for (int nt = 0; nt < 2; ++nt)
      acc[dy][nt] = f32x4{0.f, 0.f, 0.f, 0.f};

#pragma unroll
  for (int it = 0; it < 5; ++it)
    if (tid + it * 256 < 1152)
      gload16(gbase + gb[it], smem + (tid + it * 256) * 16);
  __syncthreads();

#pragma unroll
  for (int kc = 0; kc < 8; ++kc) {
    int cur = kc & 1;
    if (kc < 7) {
      char* dstb = smem + (cur ^ 1) * BUFB;
#pragma unroll
      for (int it = 0; it < 5; ++it)
        if (tid + it * 256 < 1152)
          gload16(gbase + gb[it] + (long)(kc + 1) * 64, dstb + (tid + it * 256) * 16);
    }
    const unsigned short* bufc = sb + cur * (BUFB / 2);
#pragma unroll
    for (int dy = 0; dy < 9; ++dy) {
      int rbase = (wv + dy) * 96;
#pragma unroll
      for (int nt = 0; nt < 2; ++nt) {
        int sl = rbase + (nt * 16 + n16) * 4 + hi;
        int ph = (sl & ~7) | ((sl & 7) ^ ((sl >> 3) & 7));
        bf16x8 bfr = *(const bf16x8*)(bufc + ph * 8);
        acc[dy][nt] = __builtin_amdgcn_mfma_f32_16x16x32_bf16(afr[kc], bfr, acc[dy][nt], 0, 0, 0);
      }
    }
    __syncthreads();
  }

  float* lds_o = (float*)smem;
  float* dt = (float*)(smem + 64 * ND_ * 4);
#pragma unroll
  for (int dy = 0; dy < 9; ++dy)
#pragma unroll
    for (int nt = 0; nt < 2; ++nt)
#pragma unroll
      for (int r = 0; r < 4; ++r) {
        int m = hi * 4 + r;
        int dx = nt * 16 + n16 - m - 4;
        if (dx >= -4 && dx <= 4) {
          int d = (8 - dy) * 9 + (4 - dx);
          lds_o[(wv * 16 + m) * ND_ + d] = acc[dy][nt][r];
        }
      }
  if (tid < 64) {
    int ty = tid >> 4, tx = tid & 15;
    int xq = x0 + tx, yq = y0 + ty;
    float v = 0.f;
    if (xq < W) {
      long pidx = (long)b * HW + (long)yq * W + xq;
      v = dwp[0] * expf(-fabsf(d1[pidx] - d2[pidx]));
    }
    dt[tid] = v;
  }
  __syncthreads();
  long obase = (long)b * ND_ * HW;
  for (int it = 0; it < 21; ++it) {
    int flat = it * 256 + tid;
    if (flat < 64 * ND_) {
      int d = flat >> 6;
      int p = flat & 63;
      int xq = x0 + (p & 15);
      if (xq < W)
        out[obase + (long)d * HW + (long)(y0 + (p >> 4)) * W + xq] = lds_o[p * ND_ + d] + dt[p];
    }
  }
}

// ---------------- r4-proven corr (global-B, compact buffers) — L2/L3 ----------------
__global__ __launch_bounds__(256, 2) void corr_g(
    const unsigned short* __restrict__ f1n, const unsigned short* __restrict__ f2n,
    const float* __restrict__ d1, const float* __restrict__ d2,
    const float* __restrict__ dwp, float* __restrict__ out, int H, int W) {
  __shared__ float lds_o[64 * ND_];
  __shared__ float dt[64];
  int tid = threadIdx.x;
  int lane = tid & 63, wv = tid >> 6;
  int x0 = blockIdx.x * 16, y0 = blockIdx.y * 4, b = blockIdx.z;
  int y = y0 + wv;
  int n16 = lane & 15, hi = lane >> 4;
  long HW = (long)H * W;

  int xm = x0 + n16;
  bool aok = xm < W;
  const unsigned short* abase = f1n + ((long)b * HW + (long)y * W + xm) * C_ + hi * 8;
  bf16x8 afr[8];
#pragma unroll
  for (int ch = 0; ch < 8; ++ch) {
    u32x4 rr = {0u, 0u, 0u, 0u};
    if (aok) rr = *(const u32x4*)(abase + ch * 32);
    afr[ch] = __builtin_bit_cast(bf16x8, rr);
  }

  f32x4 acc[9][2];
#pragma unroll
  for (int dy = 0; dy < 9; ++dy)
#pragma unroll
    for (int nt = 0; nt < 2; ++nt)
      acc[dy][nt] = f32x4{0.f, 0.f, 0.f, 0.f};

#pragma unroll
  for (int dy = 0; dy < 9; ++dy) {
    int yy = y + dy - 4;
    if (yy >= 0 && yy < H) {
      const unsigned short* brow = f2n + ((long)b * HW + (long)yy * W) * C_;
#pragma unroll
      for (int nt = 0; nt < 2; ++nt) {
        int wx = x0 - 4 + nt * 16 + n16;
        bool bok = (wx >= 0) && (wx < W);
        const unsigned short* bbase = brow + (long)wx * C_ + hi * 8;
        bf16x8 bfr[8];
#pragma unroll
        for (int ch = 0; ch < 8; ++ch) {
          u32x4 rr = {0u, 0u, 0u, 0u};
          if (bok) rr = *(const u32x4*)(bbase + ch * 32);
          bfr[ch] = __builtin_bit_cast(bf16x8, rr);
        }
#pragma unroll
        for (int ch = 0; ch < 8; ++ch)
          acc[dy][nt] = __builtin_amdgcn_mfma_f32_16x16x32_bf16(afr[ch], bfr[ch], acc[dy][nt], 0, 0, 0);
      }
    }
  }

#pragma unroll
  for (int dy = 0; dy < 9; ++dy)
#pragma unroll
    for (int nt = 0; nt < 2; ++nt)
#pragma unroll
      for (int r = 0; r < 4; ++r) {
        int m = hi * 4 + r;
        int dx = nt * 16 + n16 - m - 4;
        if (dx >= -4 && dx <= 4) {
          int d = (8 - dy) * 9 + (4 - dx);
          lds_o[(wv * 16 + m) * ND_ + d] = acc[dy][nt][r];
        }
      }
  if (tid < 64) {
    int ty = tid >> 4, tx = tid & 15;
    int xq = x0 + tx, yq = y0 + ty;
    float v = 0.f;
    if (xq < W) {
      long pidx = (long)b * HW + (long)yq * W + xq;
      v = dwp[0] * expf(-fabsf(d1[pidx] - d2[pidx]));
    }
    dt[tid] = v;
  }
  __syncthreads();
  long obase = (long)b * ND_ * HW;
  for (int it = 0; it < 21; ++it) {
    int flat = it * 256 + tid;
    if (flat < 64 * ND_) {
      int d = flat >> 6;
      int p = flat & 63;
      int xq = x0 + (p & 15);
      if (xq < W)
        out[obase + (long)d * HW + (long)(y0 + (p >> 4)) * W + xq] = lds_o[p * ND_ + d] + dt[p];
    }
  }
}

// ---------------------------------------------------------------------------
extern "C" void kernel_launch(void* const* d_in, const int* in_sizes, int n_in,
                              void* d_out, int out_size, void* d_ws, size_t ws_size,
                              hipStream_t stream) {
  const float* f1  = (const float*)d_in[0];
  const float* f2  = (const float*)d_in[1];
  const float* dp1 = (const float*)d_in[2];
  const float* dp2 = (const float*)d_in[3];
  const float* dw  = (const float*)d_in[4];
  float* out = (float*)d_out;

  char* ws = (char*)d_ws;
  size_t off = 0;
  auto alloc = [&](size_t bytes) -> void* {
    void* p = ws + off;
    off = (off + bytes + 255) & ~(size_t)255;
    return p;
  };
  static const long HWs[4] = {25600, 6400, 1600, 400};
  float* f1p[4]; float* f2p[4]; float* d1p[4]; float* d2p[4];
  for (int l = 1; l <= 3; ++l) f1p[l] = (float*)alloc((size_t)B_ * C_ * HWs[l] * 4);
  for (int l = 1; l <= 3; ++l) f2p[l] = (float*)alloc((size_t)B_ * C_ * HWs[l] * 4);
  for (int l = 1; l <= 3; ++l) d1p[l] = (float*)alloc((size_t)B_ * HWs[l] * 4);
  for (int l = 1; l <= 3; ++l) d2p[l] = (float*)alloc((size_t)B_ * HWs[l] * 4);
  unsigned short* f1n0 = (unsigned short*)alloc((size_t)B_ * 25600 * C_ * 2);
  unsigned short* f1n1 = (unsigned short*)alloc((size_t)B_ * 6400 * C_ * 2);
  unsigned short* f2n0 = (unsigned short*)alloc((size_t)B_ * 168 * 168 * C_ * 2);
  unsigned short* f2n1 = (unsigned short*)alloc((size_t)B_ * 88 * 88 * C_ * 2);
  unsigned short* f1n2 = (unsigned short*)alloc((size_t)B_ * 1600 * C_ * 2);
  unsigned short* f2n2 = (unsigned short*)alloc((size_t)B_ * 1600 * C_ * 2);
  unsigned short* f1n3 = (unsigned short*)alloc((size_t)B_ * 400 * C_ * 2);
  unsigned short* f2n3 = (unsigned short*)alloc((size_t)B_ * 400 * C_ * 2);
  if (off > ws_size) return;   // would leave out poisoned -> recognizable absmax ~488

  // 1) pooling pyramid
  pool_level<80, 80><<<dim3((13158400 + 255) / 256), 256, 0, stream>>>(
      f1, f2, dp1, dp2, f1p[1], f2p[1], d1p[1], d2p[1]);
  pool_level<40, 40><<<dim3((3289600 + 255) / 256), 256, 0, stream>>>(
      f1p[1], f2p[1], d1p[1], d2p[1], f1p[2], f2p[2], d1p[2], d2p[2]);
  pool_level<20, 20><<<dim3((822400 + 255) / 256), 256, 0, stream>>>(
      f1p[2], f2p[2], d1p[2], d2p[2], f1p[3], f2p[3], d1p[3], d2p[3]);

  // 2) L0/L1: normalize (padded f2n) + halo zero, then staged corr
  norm_tp2<160><<<dim3(400, 1, 8), 256, 0, stream>>>(f1, f2, f1n0, f2n0);
  norm_tp2< 80><<<dim3(100, 1, 8), 256, 0, stream>>>(f1p[1], f2p[1], f1n1, f2n1);
  zero_halo<160><<<dim3(14112), 256, 0, stream>>>(f2n0);
  zero_halo< 80><<<dim3( 3872), 256, 0, stream>>>(f2n1);
  corr2<160><<<dim3(1600), 256, 0, stream>>>(f1n0, f2n0, dp1,    dp2,    dw, out);
  corr2< 80><<<dim3( 400), 256, 0, stream>>>(f1n1, f2n1, d1p[1], d2p[1], dw, out + 8294400);

  // 3) L2/L3: r4-proven compact path (distinct buffers)
  norm_tp_c<<<dim3(25, 1, 8), 256, 0, stream>>>(f1p[2], f2p[2], f1n2, f2n2, 1600);
  norm_tp_c<<<dim3( 7, 1, 8), 256, 0, stream>>>(f1p[3], f2p[3], f1n3, f2n3, 400);
  corr_g<<<dim3(3, 10, 4), 256, 0, stream>>>(f1n2, f2n2, d1p[2], d2p[2], dw, out + 10368000, 40, 40);
  corr_g<<<dim3(2,  5, 4), 256, 0, stream>>>(f1n3, f2n3, d1p[3], d2p[3], dw, out + 10886400, 20, 20);
}

// Round 9
// 278.974 us; speedup vs baseline: 1.9570x; 1.0019x over previous
//
#include <hip/hip_runtime.h>
#include <hip/hip_bf16.h>

// r9 = r8 with the idx_out compile error fixed (store is dst + 4*g).
// pool4: 4 outputs/thread, f32x4 loads/stores. Everything else r7-verbatim.

#define B_ 4
#define C_ 256
#define ND_ 81

typedef float  f32x4 __attribute__((ext_vector_type(4)));
typedef float  f32x2 __attribute__((ext_vector_type(2)));
typedef unsigned int u32x4 __attribute__((ext_vector_type(4)));
typedef __bf16 bf16x8 __attribute__((ext_vector_type(8)));
typedef unsigned short u16x4 __attribute__((ext_vector_type(4)));

__device__ __forceinline__ unsigned short f2bf(float f) {
  unsigned int u = __builtin_bit_cast(unsigned int, f);
  u += 0x7FFFu + ((u >> 16) & 1u);   // RNE
  return (unsigned short)(u >> 16);
}

__device__ __forceinline__ void gload16(const void* g, void* l) {
  __builtin_amdgcn_global_load_lds(
      (const __attribute__((address_space(1))) unsigned int*)g,
      (__attribute__((address_space(3))) unsigned int*)l, 16, 0, 0);
}

// ---------------- 2x2 average pooling, 4 outputs/thread ----------------
template<int Ho, int Wo>
__global__ __launch_bounds__(256) void pool4(
    const float* __restrict__ f1i, const float* __restrict__ f2i,
    const float* __restrict__ d1i, const float* __restrict__ d2i,
    float* __restrict__ f1o, float* __restrict__ f2o,
    float* __restrict__ d1o, float* __restrict__ d2o) {
  constexpr long HWo = (long)Ho * Wo;
  constexpr long G4F = (long)B_ * C_ * HWo / 4;   // fmap quad-groups
  constexpr long G4D = (long)B_ * HWo / 4;        // depth quad-groups
  constexpr long N   = 2 * G4F + 2 * G4D;
  long idx = (long)blockIdx.x * blockDim.x + threadIdx.x;
  if (idx >= N) return;
  const float* src; float* dst; long g = idx;
  if      (g < G4F)           { src = f1i; dst = f1o; }
  else if (g < 2*G4F)         { src = f2i; dst = f2o; g -= G4F; }
  else if (g < 2*G4F + G4D)   { src = d1i; dst = d1o; g -= 2*G4F; }
  else                        { src = d2i; dst = d2o; g -= 2*G4F + G4D; }
  constexpr long GP = HWo / 4;        // quad-groups per plane
  long plane = g / GP;                // constexpr divisor -> magic mul
  long gp    = g - plane * GP;
  int  yo    = (int)(gp / (Wo / 4));
  int  xg    = (int)(gp - (long)yo * (Wo / 4));
  constexpr int Wi = 2 * Wo;
  const float* p0 = src + (plane * (2 * Ho) + 2 * yo) * (long)Wi + 8 * xg;
  f32x4 a0 = *(const f32x4*)p0;
  f32x4 a1 = *(const f32x4*)(p0 + 4);
  f32x4 b0 = *(const f32x4*)(p0 + Wi);
  f32x4 b1 = *(const f32x4*)(p0 + Wi + 4);
  f32x4 o;
  o.x = 0.25f * (a0.x + a0.y + b0.x + b0.y);
  o.y = 0.25f * (a0.z + a0.w + b0.z + b0.w);
  o.z = 0.25f * (a1.x + a1.y + b1.x + b1.y);
  o.w = 0.25f * (a1.z + a1.w + b1.z + b1.w);
  *(f32x4*)(dst + 4 * g) = o;
}

// ------- normalize + transpose, dst2 zero-halo-padded (L0/L1 path) -------
template<int W>
__global__ __launch_bounds__(256) void norm_tp2(
    const float* __restrict__ src1, const float* __restrict__ src2,
    unsigned short* __restrict__ dst1, unsigned short* __restrict__ dst2) {
  constexpr int HW = W * W, Wp = W + 8;
  __shared__ unsigned short raw[64 * 260];
  __shared__ float ssp[4][64];
  __shared__ float inv[64];
  int tid = threadIdx.x;
  int lane = tid & 63, w = tid >> 6;
  long pix0 = (long)blockIdx.x * 64;
  int z = blockIdx.z, b = z >> 1;
  bool pad = (z & 1) != 0;
  const float* src = pad ? src2 : src1;
  unsigned short* dst = pad ? dst2 : dst1;
  bool ok = (pix0 + lane) < HW;
  const float* base = src + (long)b * C_ * HW + pix0 + lane;

  float ss = 0.f;
  float vv[16];
  for (int cb = 0; cb < 64; cb += 16) {
    int c0 = w * 64 + cb;
#pragma unroll
    for (int j = 0; j < 16; ++j)
      vv[j] = ok ? base[(long)(c0 + j) * HW] : 0.f;
#pragma unroll
    for (int g = 0; g < 4; ++g) {
      u16x4 pk;
#pragma unroll
      for (int j = 0; j < 4; ++j) {
        float v = vv[g * 4 + j];
        ss += v * v;
        pk[j] = f2bf(v);
      }
      *(u16x4*)&raw[lane * 260 + c0 + g * 4] = pk;
    }
  }
  ssp[w][lane] = ss;
  __syncthreads();
  if (tid < 64) {
    float s = ssp[0][tid] + ssp[1][tid] + ssp[2][tid] + ssp[3][tid];
    inv[tid] = 1.f / fmaxf(sqrtf(s), 1e-12f);
  }
  __syncthreads();

  int c4 = lane * 4;
  for (int p = w; p < 64; p += 4) {
    long pix = pix0 + p;
    if (pix < HW) {
      long off;
      if (pad) {
        int y = (int)(pix / W);
        int x = (int)(pix - (long)y * W);
        off = (((long)b * Wp + (y + 4)) * Wp + (x + 4)) * C_ + c4;
      } else {
        off = ((long)b * HW + pix) * C_ + c4;
      }
      u16x4 r = *(const u16x4*)&raw[p * 260 + c4];
      float sc = inv[p];
      u16x4 o;
#pragma unroll
      for (int j = 0; j < 4; ++j) {
        float v = __builtin_bit_cast(float, ((unsigned int)r[j]) << 16) * sc;
        o[j] = f2bf(v);
      }
      *(u16x4*)&dst[off] = o;
    }
  }
}

// ------- r4-proven: normalize + transpose, both compact (L2/L3 path) -------
__global__ __launch_bounds__(256) void norm_tp_c(
    const float* __restrict__ src1, const float* __restrict__ src2,
    unsigned short* __restrict__ dst1, unsigned short* __restrict__ dst2, int HW_) {
  __shared__ unsigned short raw[64 * 260];
  __shared__ float ssp[4][64];
  __shared__ float inv[64];
  int tid = threadIdx.x;
  int lane = tid & 63, w = tid >> 6;
  long HW = HW_;
  long pix0 = (long)blockIdx.x * 64;
  int z = blockIdx.z, b = z >> 1;
  const float* src = (z & 1) ? src2 : src1;
  unsigned short* dst = (z & 1) ? dst2 : dst1;
  bool ok = (pix0 + lane) < HW;
  const float* base = src + (long)b * C_ * HW + pix0 + lane;

  float ss = 0.f;
  float vv[16];
  for (int cb = 0; cb < 64; cb += 16) {
    int c0 = w * 64 + cb;
#pragma unroll
    for (int j = 0; j < 16; ++j)
      vv[j] = ok ? base[(long)(c0 + j) * HW] : 0.f;
#pragma unroll
    for (int g = 0; g < 4; ++g) {
      u16x4 pk;
#pragma unroll
      for (int j = 0; j < 4; ++j) {
        float v = vv[g * 4 + j];
        ss += v * v;
        pk[j] = f2bf(v);
      }
      *(u16x4*)&raw[lane * 260 + c0 + g * 4] = pk;
    }
  }
  ssp[w][lane] = ss;
  __syncthreads();
  if (tid < 64) {
    float s = ssp[0][tid] + ssp[1][tid] + ssp[2][tid] + ssp[3][tid];
    inv[tid] = 1.f / fmaxf(sqrtf(s), 1e-12f);
  }
  __syncthreads();
  int c4 = lane * 4;
  unsigned short* dbase = dst + ((long)b * HW + pix0) * C_;
  for (int p = w; p < 64; p += 4) {
    if (pix0 + p < HW) {
      u16x4 r = *(const u16x4*)&raw[p * 260 + c4];
      float sc = inv[p];
      u16x4 o;
#pragma unroll
      for (int j = 0; j < 4; ++j) {
        float v = __builtin_bit_cast(float, ((unsigned int)r[j]) << 16) * sc;
        o[j] = f2bf(v);
      }
      *(u16x4*)&dbase[(long)p * C_ + c4] = o;
    }
  }
}

// ------- zero the 4px halo of a padded [b][y'][x'][c] bf16 buffer -------
template<int W>
__global__ void zero_halo(unsigned short* __restrict__ fp) {
  constexpr int Wp = W + 8;
  constexpr long UN = (long)B_ * Wp * Wp * 32;
  long u = (long)blockIdx.x * 256 + threadIdx.x;
  if (u >= UN) return;
  long px = u >> 5;
  long pp = px % ((long)Wp * Wp);
  int y = (int)(pp / Wp), x = (int)(pp - (long)(pp / Wp) * Wp);
  if (y < 4 || y >= Wp - 4 || x < 4 || x >= Wp - 4) {
    u16x4 z4 = {0, 0, 0, 0};
    *(u16x4*)&fp[u * 8] = z4;
  }
}

// ---------------- corr2: LDS-staged, K-chunked, XCD-swizzled (L0/L1) ----------------
template<int W>
__global__ __launch_bounds__(256, 3) void corr2(
    const unsigned short* __restrict__ f1n, const unsigned short* __restrict__ f2pd,
    const float* __restrict__ d1, const float* __restrict__ d2,
    const float* __restrict__ dwp, float* __restrict__ out) {
  constexpr int H = W, Wp = W + 8, Hp = H + 8;
  constexpr int GX = (W + 15) / 16, GY = H / 4;
  constexpr int NB = GX * GY * B_;
  constexpr int CPX = NB / 8;
  constexpr int BUFB = 18944;
  __shared__ char smem[2 * BUFB];
  unsigned short* sb = (unsigned short*)smem;

  int tid = threadIdx.x;
  int lane = tid & 63, wv = tid >> 6;
  int n16 = lane & 15, hi = lane >> 4;

  int f = blockIdx.x;
  int nf = (f & 7) * CPX + (f >> 3);
  int j = nf % GY;
  int rest = nf / GY;
  int i = rest % GX;
  int b = rest / GX;
  int x0 = i * 16, y0 = j * 4, y = y0 + wv;
  long HW = (long)W * H;

  int xm = x0 + n16;
  bool aok = xm < W;
  const unsigned short* abase = f1n + ((long)b * HW + (long)y * W + xm) * C_ + hi * 8;
  bf16x8 afr[8];
#pragma unroll
  for (int kc = 0; kc < 8; ++kc) {
    u32x4 rr = {0u, 0u, 0u, 0u};
    if (aok) rr = *(const u32x4*)(abase + kc * 32);
    afr[kc] = __builtin_bit_cast(bf16x8, rr);
  }

  const char* gbase = (const char*)f2pd;
  long gb[5];
#pragma unroll
  for (int it = 0; it < 5; ++it) {
    int u = tid + it * 256;
    int u2 = (u < 1152) ? u : 0;
    int sl = (u2 & ~7) | ((u2 & 7) ^ ((u2 >> 3) & 7));
    int px = sl >> 2, s = sl & 3;
    int row = px / 24, col = px - row * 24;
    int gx = x0 + col; if (gx > Wp - 1) gx = Wp - 1;
    int gy = y0 + row;
    gb[it] = (((long)b * Hp + gy) * Wp + gx) * 512 + s * 16;
  }

  f32x4 acc[9][2];
#pragma unroll
  for (int dy = 0; dy < 9; ++dy)
#pragma unroll
    for (int nt = 0; nt < 2; ++nt)
      acc[dy][nt] = f32x4{0.f, 0.f, 0.f, 0.f};

#pragma unroll
  for (int it = 0; it < 5; ++it)
    if (tid + it * 256 < 1152)
      gload16(gbase + gb[it], smem + (tid + it * 256) * 16);
  __syncthreads();

#pragma unroll
  for (int kc = 0; kc < 8; ++kc) {
    int cur = kc & 1;
    if (kc < 7) {
      char* dstb = smem + (cur ^ 1) * BUFB;
#pragma unroll
      for (int it = 0; it < 5; ++it)
        if (tid + it * 256 < 1152)
          gload16(gbase + gb[it] + (long)(kc + 1) * 64, dstb + (tid + it * 256) * 16);
    }
    const unsigned short* bufc = sb + cur * (BUFB / 2);
#pragma unroll
    for (int dy = 0; dy < 9; ++dy) {
      int rbase = (wv + dy) * 96;
#pragma unroll
      for (int nt = 0; nt < 2; ++nt) {
        int sl = rbase + (nt * 16 + n16) * 4 + hi;
        int ph = (sl & ~7) | ((sl & 7) ^ ((sl >> 3) & 7));
        bf16x8 bfr = *(const bf16x8*)(bufc + ph * 8);
        acc[dy][nt] = __builtin_amdgcn_mfma_f32_16x16x32_bf16(afr[kc], bfr, acc[dy][nt], 0, 0, 0);
      }
    }
    __syncthreads();
  }

  float* lds_o = (float*)smem;
  float* dt = (float*)(smem + 64 * ND_ * 4);
#pragma unroll
  for (int dy = 0; dy < 9; ++dy)
#pragma unroll
    for (int nt = 0; nt < 2; ++nt)
#pragma unroll
      for (int r = 0; r < 4; ++r) {
        int m = hi * 4 + r;
        int dx = nt * 16 + n16 - m - 4;
        if (dx >= -4 && dx <= 4) {
          int d = (8 - dy) * 9 + (4 - dx);
          lds_o[(wv * 16 + m) * ND_ + d] = acc[dy][nt][r];
        }
      }
  if (tid < 64) {
    int ty = tid >> 4, tx = tid & 15;
    int xq = x0 + tx, yq = y0 + ty;
    float v = 0.f;
    if (xq < W) {
      long pidx = (long)b * HW + (long)yq * W + xq;
      v = dwp[0] * expf(-fabsf(d1[pidx] - d2[pidx]));
    }
    dt[tid] = v;
  }
  __syncthreads();
  long obase = (long)b * ND_ * HW;
  for (int it = 0; it < 21; ++it) {
    int flat = it * 256 + tid;
    if (flat < 64 * ND_) {
      int d = flat >> 6;
      int p = flat & 63;
      int xq = x0 + (p & 15);
      if (xq < W)
        out[obase + (long)d * HW + (long)(y0 + (p >> 4)) * W + xq] = lds_o[p * ND_ + d] + dt[p];
    }
  }
}

// ---------------- r4-proven corr (global-B, compact buffers) — L2/L3 ----------------
__global__ __launch_bounds__(256, 2) void corr_g(
    const unsigned short* __restrict__ f1n, const unsigned short* __restrict__ f2n,
    const float* __restrict__ d1, const float* __restrict__ d2,
    const float* __restrict__ dwp, float* __restrict__ out, int H, int W) {
  __shared__ float lds_o[64 * ND_];
  __shared__ float dt[64];
  int tid = threadIdx.x;
  int lane = tid & 63, wv = tid >> 6;
  int x0 = blockIdx.x * 16, y0 = blockIdx.y * 4, b = blockIdx.z;
  int y = y0 + wv;
  int n16 = lane & 15, hi = lane >> 4;
  long HW = (long)H * W;

  int xm = x0 + n16;
  bool aok = xm < W;
  const unsigned short* abase = f1n + ((long)b * HW + (long)y * W + xm) * C_ + hi * 8;
  bf16x8 afr[8];
#pragma unroll
  for (int ch = 0; ch < 8; ++ch) {
    u32x4 rr = {0u, 0u, 0u, 0u};
    if (aok) rr = *(const u32x4*)(abase + ch * 32);
    afr[ch] = __builtin_bit_cast(bf16x8, rr);
  }

  f32x4 acc[9][2];
#pragma unroll
  for (int dy = 0; dy < 9; ++dy)
#pragma unroll
    for (int nt = 0; nt < 2; ++nt)
      acc[dy][nt] = f32x4{0.f, 0.f, 0.f, 0.f};

#pragma unroll
  for (int dy = 0; dy < 9; ++dy) {
    int yy = y + dy - 4;
    if (yy >= 0 && yy < H) {
      const unsigned short* brow = f2n + ((long)b * HW + (long)yy * W) * C_;
#pragma unroll
      for (int nt = 0; nt < 2; ++nt) {
        int wx = x0 - 4 + nt * 16 + n16;
        bool bok = (wx >= 0) && (wx < W);
        const unsigned short* bbase = brow + (long)wx * C_ + hi * 8;
        bf16x8 bfr[8];
#pragma unroll
        for (int ch = 0; ch < 8; ++ch) {
          u32x4 rr = {0u, 0u, 0u, 0u};
          if (bok) rr = *(const u32x4*)(bbase + ch * 32);
          bfr[ch] = __builtin_bit_cast(bf16x8, rr);
        }
#pragma unroll
        for (int ch = 0; ch < 8; ++ch)
          acc[dy][nt] = __builtin_amdgcn_mfma_f32_16x16x32_bf16(afr[ch], bfr[ch], acc[dy][nt], 0, 0, 0);
      }
    }
  }

#pragma unroll
  for (int dy = 0; dy < 9; ++dy)
#pragma unroll
    for (int nt = 0; nt < 2; ++nt)
#pragma unroll
      for (int r = 0; r < 4; ++r) {
        int m = hi * 4 + r;
        int dx = nt * 16 + n16 - m - 4;
        if (dx >= -4 && dx <= 4) {
          int d = (8 - dy) * 9 + (4 - dx);
          lds_o[(wv * 16 + m) * ND_ + d] = acc[dy][nt][r];
        }
      }
  if (tid < 64) {
    int ty = tid >> 4, tx = tid & 15;
    int xq = x0 + tx, yq = y0 + ty;
    float v = 0.f;
    if (xq < W) {
      long pidx = (long)b * HW + (long)yq * W + xq;
      v = dwp[0] * expf(-fabsf(d1[pidx] - d2[pidx]));
    }
    dt[tid] = v;
  }
  __syncthreads();
  long obase = (long)b * ND_ * HW;
  for (int it = 0; it < 21; ++it) {
    int flat = it * 256 + tid;
    if (flat < 64 * ND_) {
      int d = flat >> 6;
      int p = flat & 63;
      int xq = x0 + (p & 15);
      if (xq < W)
        out[obase + (long)d * HW + (long)(y0 + (p >> 4)) * W + xq] = lds_o[p * ND_ + d] + dt[p];
    }
  }
}

// ---------------------------------------------------------------------------
extern "C" void kernel_launch(void* const* d_in, const int* in_sizes, int n_in,
                              void* d_out, int out_size, void* d_ws, size_t ws_size,
                              hipStream_t stream) {
  const float* f1  = (const float*)d_in[0];
  const float* f2  = (const float*)d_in[1];
  const float* dp1 = (const float*)d_in[2];
  const float* dp2 = (const float*)d_in[3];
  const float* dw  = (const float*)d_in[4];
  float* out = (float*)d_out;

  char* ws = (char*)d_ws;
  size_t off = 0;
  auto alloc = [&](size_t bytes) -> void* {
    void* p = ws + off;
    off = (off + bytes + 255) & ~(size_t)255;
    return p;
  };
  static const long HWs[4] = {25600, 6400, 1600, 400};
  float* f1p[4]; float* f2p[4]; float* d1p[4]; float* d2p[4];
  for (int l = 1; l <= 3; ++l) f1p[l] = (float*)alloc((size_t)B_ * C_ * HWs[l] * 4);
  for (int l = 1; l <= 3; ++l) f2p[l] = (float*)alloc((size_t)B_ * C_ * HWs[l] * 4);
  for (int l = 1; l <= 3; ++l) d1p[l] = (float*)alloc((size_t)B_ * HWs[l] * 4);
  for (int l = 1; l <= 3; ++l) d2p[l] = (float*)alloc((size_t)B_ * HWs[l] * 4);
  unsigned short* f1n0 = (unsigned short*)alloc((size_t)B_ * 25600 * C_ * 2);
  unsigned short* f1n1 = (unsigned short*)alloc((size_t)B_ * 6400 * C_ * 2);
  unsigned short* f2n0 = (unsigned short*)alloc((size_t)B_ * 168 * 168 * C_ * 2);
  unsigned short* f2n1 = (unsigned short*)alloc((size_t)B_ * 88 * 88 * C_ * 2);
  unsigned short* f1n2 = (unsigned short*)alloc((size_t)B_ * 1600 * C_ * 2);
  unsigned short* f2n2 = (unsigned short*)alloc((size_t)B_ * 1600 * C_ * 2);
  unsigned short* f1n3 = (unsigned short*)alloc((size_t)B_ * 400 * C_ * 2);
  unsigned short* f2n3 = (unsigned short*)alloc((size_t)B_ * 400 * C_ * 2);
  if (off > ws_size) return;

  // 1) pooling pyramid (4 outputs/thread)
  pool4<80, 80><<<dim3(12850), 256, 0, stream>>>(
      f1, f2, dp1, dp2, f1p[1], f2p[1], d1p[1], d2p[1]);
  pool4<40, 40><<<dim3(3213), 256, 0, stream>>>(
      f1p[1], f2p[1], d1p[1], d2p[1], f1p[2], f2p[2], d1p[2], d2p[2]);
  pool4<20, 20><<<dim3(804), 256, 0, stream>>>(
      f1p[2], f2p[2], d1p[2], d2p[2], f1p[3], f2p[3], d1p[3], d2p[3]);

  // 2) L0/L1: normalize (padded f2n) + halo zero, then staged corr
  norm_tp2<160><<<dim3(400, 1, 8), 256, 0, stream>>>(f1, f2, f1n0, f2n0);
  norm_tp2< 80><<<dim3(100, 1, 8), 256, 0, stream>>>(f1p[1], f2p[1], f1n1, f2n1);
  zero_halo<160><<<dim3(14112), 256, 0, stream>>>(f2n0);
  zero_halo< 80><<<dim3( 3872), 256, 0, stream>>>(f2n1);
  corr2<160><<<dim3(1600), 256, 0, stream>>>(f1n0, f2n0, dp1,    dp2,    dw, out);
  corr2< 80><<<dim3( 400), 256, 0, stream>>>(f1n1, f2n1, d1p[1], d2p[1], dw, out + 8294400);

  // 3) L2/L3: r4-proven compact path (distinct buffers)
  norm_tp_c<<<dim3(25, 1, 8), 256, 0, stream>>>(f1p[2], f2p[2], f1n2, f2n2, 1600);
  norm_tp_c<<<dim3( 7, 1, 8), 256, 0, stream>>>(f1p[3], f2p[3], f1n3, f2n3, 400);
  corr_g<<<dim3(3, 10, 4), 256, 0, stream>>>(f1n2, f2n2, d1p[2], d2p[2], dw, out + 10368000, 40, 40);
  corr_g<<<dim3(2,  5, 4), 256, 0, stream>>>(f1n3, f2n3, d1p[3], d2p[3], dw, out + 10886400, 20, 20);
}